// Round 6
// baseline (483.199 us; speedup 1.0000x reference)
//
#include <hip/hip_runtime.h>
#include <hip/hip_bf16.h>

#define D 1024

typedef unsigned int u32;
typedef __attribute__((ext_vector_type(4))) unsigned int u32x4;

__device__ __forceinline__ float bflo(u32 u) { return __uint_as_float(u << 16); }
__device__ __forceinline__ float bfhi(u32 u) { return __uint_as_float(u & 0xffff0000u); }
__device__ __forceinline__ float bf1(const void* p, int j) {
    unsigned short s = ((const unsigned short*)p)[j];
    return __uint_as_float(((u32)s) << 16);
}

__device__ __forceinline__ float waveReduceSum(float v) {
#pragma unroll
    for (int off = 32; off > 0; off >>= 1) v += __shfl_xor(v, off, 64);
    return v;
}

// per-wave dtype probe: bf16 low-half exponents are sane; fp32 low halves ~random
__device__ __forceinline__ int probeBf16(const void* ht, int lane) {
    u32 w = ((const u32*)ht)[lane];
    u32 e = (w >> 7) & 0xFF;
    float c = (e >= 100 && e <= 126) ? 1.f : 0.f;
    c = waveReduceSum(c);
    return (c >= 56.f) ? 1 : 0;
}

__device__ __forceinline__ float rowDotHt(const void* W, const void* ht,
                                          int j, int lane, int isBf16) {
    float s = 0.f;
    if (isBf16) {
        const u32x4* wrow = (const u32x4*)((const __hip_bfloat16*)W + (size_t)j * D);
        const u32x4* hv = (const u32x4*)ht;
#pragma unroll
        for (int half = 0; half < 2; ++half) {
            u32x4 a = wrow[half * 64 + lane];
            u32x4 b = hv[half * 64 + lane];
#pragma unroll
            for (int t = 0; t < 4; ++t) {
                s += bflo(a[t]) * bflo(b[t]);
                s += bfhi(a[t]) * bfhi(b[t]);
            }
        }
    } else {
        const float4* wrow = (const float4*)((const float*)W + (size_t)j * D);
        const float4* hv = (const float4*)ht;
#pragma unroll
        for (int t = 0; t < 4; ++t) {
            float4 a = wrow[t * 64 + lane];
            float4 b = hv[t * 64 + lane];
            s += a.x * b.x + a.y * b.y + a.z * b.z + a.w * b.w;
        }
    }
    return waveReduceSum(s);
}

// waves 0-3: q[j] = W0[j].h_t + b0[j];  waves 4-7: t2[j] = W2[j].h_t + b1[j] + b2[j].
// Also zeros the ticket counter.
__global__ __launch_bounds__(512) void k_q(const void* __restrict__ W0,
                                           const void* __restrict__ b0,
                                           const void* __restrict__ W2,
                                           const void* __restrict__ b1,
                                           const void* __restrict__ b2,
                                           const void* __restrict__ ht,
                                           float* __restrict__ q,
                                           float* __restrict__ t2,
                                           int* __restrict__ counter) {
    int wid = threadIdx.x >> 6, lane = threadIdx.x & 63;
    int isBf16 = probeBf16(ht, lane);
    if (blockIdx.x == 0 && threadIdx.x == 0) *counter = 0;
    int j = blockIdx.x * 4 + (wid & 3);
    if (wid < 4) {
        float s = rowDotHt(W0, ht, j, lane, isBf16);
        if (lane == 0) {
            float bias = isBf16 ? bf1(b0, j) : ((const float*)b0)[j];
            q[j] = s + bias;
        }
    } else {
        float s = rowDotHt(W2, ht, j, lane, isBf16);
        if (lane == 0) {
            float bb = isBf16 ? (bf1(b1, j) + bf1(b2, j))
                              : (((const float*)b1)[j] + ((const float*)b2)[j]);
            t2[j] = s + bb;
        }
    }
}

// Fused single pass: w_i = exp(exp(H_i.q)); acc += w_i * H_i in registers.
// 2-row ILP; __launch_bounds__(512,4) keeps the ~90-reg working set live
// (R4 post-mortem: default budget of 64 VGPRs serialized the pipeline).
// Block partials -> accp; last-done block (fence+ticket) reduces to e_s, Ls.
#define PB 512  // k_pass grid blocks
__global__ __launch_bounds__(512, 4) void k_pass(const void* __restrict__ Hm,
                                                 const void* __restrict__ ht,
                                                 const float* __restrict__ q,
                                                 float* __restrict__ accp,  // [PB][D]
                                                 float* __restrict__ lvals, // [PB]
                                                 float* __restrict__ e_s,
                                                 float* __restrict__ Ls,
                                                 int* __restrict__ counter,
                                                 int N) {
    __shared__ float lacc[8][D];
    __shared__ float ll[8];
    __shared__ int isLast;
    int wid = threadIdx.x >> 6, lane = threadIdx.x & 63;
    int isBf16 = probeBf16(ht, lane);

    int col[16];
    if (isBf16) {
#pragma unroll
        for (int j = 0; j < 8; ++j) { col[j] = lane * 8 + j; col[8 + j] = 512 + lane * 8 + j; }
    } else {
#pragma unroll
        for (int t = 0; t < 4; ++t)
#pragma unroll
            for (int u = 0; u < 4; ++u) col[t * 4 + u] = t * 256 + lane * 4 + u;
    }
    float qr[16];
#pragma unroll
    for (int j = 0; j < 16; ++j) qr[j] = q[col[j]];

    float l = 0.f;
    float acc[16];
#pragma unroll
    for (int j = 0; j < 16; ++j) acc[j] = 0.f;

    const int totalWaves = PB * 8;
    int gw = blockIdx.x * 8 + wid;
    int r = gw;
    for (; r + totalWaves < N; r += 2 * totalWaves) {
        float h0[16], h1[16];
        if (isBf16) {
            const u32x4* hr0 = (const u32x4*)((const __hip_bfloat16*)Hm + (size_t)r * D);
            const u32x4* hr1 = (const u32x4*)((const __hip_bfloat16*)Hm + (size_t)(r + totalWaves) * D);
            u32x4 a0 = hr0[lane], b0v = hr0[64 + lane];
            u32x4 a1 = hr1[lane], b1v = hr1[64 + lane];
#pragma unroll
            for (int t = 0; t < 4; ++t) {
                h0[2 * t] = bflo(a0[t]);     h0[2 * t + 1] = bfhi(a0[t]);
                h0[8 + 2 * t] = bflo(b0v[t]); h0[8 + 2 * t + 1] = bfhi(b0v[t]);
                h1[2 * t] = bflo(a1[t]);     h1[2 * t + 1] = bfhi(a1[t]);
                h1[8 + 2 * t] = bflo(b1v[t]); h1[8 + 2 * t + 1] = bfhi(b1v[t]);
            }
        } else {
            const float4* hr0 = (const float4*)((const float*)Hm + (size_t)r * D);
            const float4* hr1 = (const float4*)((const float*)Hm + (size_t)(r + totalWaves) * D);
#pragma unroll
            for (int t = 0; t < 4; ++t) {
                float4 a = hr0[t * 64 + lane];
                float4 b = hr1[t * 64 + lane];
                h0[t * 4] = a.x; h0[t * 4 + 1] = a.y; h0[t * 4 + 2] = a.z; h0[t * 4 + 3] = a.w;
                h1[t * 4] = b.x; h1[t * 4 + 1] = b.y; h1[t * 4 + 2] = b.z; h1[t * 4 + 3] = b.w;
            }
        }
        float d0 = 0.f, d1 = 0.f;
#pragma unroll
        for (int j = 0; j < 16; ++j) { d0 += h0[j] * qr[j]; d1 += h1[j] * qr[j]; }
#pragma unroll
        for (int off = 32; off > 0; off >>= 1) {
            d0 += __shfl_xor(d0, off, 64);
            d1 += __shfl_xor(d1, off, 64);
        }
        float p0 = __expf(__expf(d0));
        float p1 = __expf(__expf(d1));
        l += p0 + p1;
#pragma unroll
        for (int j = 0; j < 16; ++j) acc[j] += p0 * h0[j] + p1 * h1[j];
    }
    if (r < N) {
        float h0[16];
        if (isBf16) {
            const u32x4* hr0 = (const u32x4*)((const __hip_bfloat16*)Hm + (size_t)r * D);
            u32x4 a0 = hr0[lane], b0v = hr0[64 + lane];
#pragma unroll
            for (int t = 0; t < 4; ++t) {
                h0[2 * t] = bflo(a0[t]);     h0[2 * t + 1] = bfhi(a0[t]);
                h0[8 + 2 * t] = bflo(b0v[t]); h0[8 + 2 * t + 1] = bfhi(b0v[t]);
            }
        } else {
            const float4* hr0 = (const float4*)((const float*)Hm + (size_t)r * D);
#pragma unroll
            for (int t = 0; t < 4; ++t) {
                float4 a = hr0[t * 64 + lane];
                h0[t * 4] = a.x; h0[t * 4 + 1] = a.y; h0[t * 4 + 2] = a.z; h0[t * 4 + 3] = a.w;
            }
        }
        float d0 = 0.f;
#pragma unroll
        for (int j = 0; j < 16; ++j) d0 += h0[j] * qr[j];
        d0 = waveReduceSum(d0);
        float p0 = __expf(__expf(d0));
        l += p0;
#pragma unroll
        for (int j = 0; j < 16; ++j) acc[j] += p0 * h0[j];
    }

    // block combine
#pragma unroll
    for (int j = 0; j < 16; ++j) lacc[wid][col[j]] = acc[j];
    if (lane == 0) ll[wid] = l;
    __syncthreads();
    float* dst = accp + (size_t)blockIdx.x * D;
    for (int k = threadIdx.x; k < D; k += 512) {
        float s = 0.f;
#pragma unroll
        for (int w = 0; w < 8; ++w) s += lacc[w][k];
        dst[k] = s;
    }
    if (threadIdx.x == 0) {
        float s = 0.f;
#pragma unroll
        for (int w = 0; w < 8; ++w) s += ll[w];
        lvals[blockIdx.x] = s;
    }

    // last-done block reduces partials (stream-k fixup: no extra launch)
    __threadfence();
    if (threadIdx.x == 0) {
        int t = atomicAdd(counter, 1);
        isLast = (t == (int)gridDim.x - 1);
    }
    __syncthreads();
    if (!isLast) return;
    __threadfence();
    {
        int c = (threadIdx.x & 255) * 4;
        if (threadIdx.x < 256) {
            float4 s = {0.f, 0.f, 0.f, 0.f};
            for (int b = 0; b < PB; ++b) {
                float4 v = *(const float4*)(accp + (size_t)b * D + c);
                s.x += v.x; s.y += v.y; s.z += v.z; s.w += v.w;
            }
            *(float4*)(e_s + c) = s;
        } else if (threadIdx.x >= 256 && threadIdx.x < 320) {
            float ls = 0.f;
            for (int b = lane; b < PB; b += 64) ls += lvals[b];
            ls = waveReduceSum(ls);
            if (lane == 0) *Ls = ls;
        }
    }
}

// out[j] = tanh(W1[j].e_s / Ls + t2[j])
__global__ __launch_bounds__(256) void k_out(const void* __restrict__ W1,
                                             const void* __restrict__ ht,
                                             const float* __restrict__ e_s,
                                             const float* __restrict__ t2,
                                             const float* __restrict__ Ls,
                                             void* __restrict__ out) {
    int wid = threadIdx.x >> 6, lane = threadIdx.x & 63;
    int j = blockIdx.x * 4 + wid;
    int isBf16 = probeBf16(ht, lane);
    float s1 = 0.f;
    if (isBf16) {
        const u32x4* w1r = (const u32x4*)((const __hip_bfloat16*)W1 + (size_t)j * D);
        int c0 = lane * 8;
#pragma unroll
        for (int half = 0; half < 2; ++half) {
            u32x4 a = w1r[half * 64 + lane];
            const float4* ev = (const float4*)(e_s + half * 512 + c0);
            float4 ea = ev[0], eb = ev[1];
            float e[8] = {ea.x, ea.y, ea.z, ea.w, eb.x, eb.y, eb.z, eb.w};
#pragma unroll
            for (int t = 0; t < 4; ++t)
                s1 += bflo(a[t]) * e[2 * t] + bfhi(a[t]) * e[2 * t + 1];
        }
    } else {
        const float4* w1r = (const float4*)((const float*)W1 + (size_t)j * D);
        const float4* ev = (const float4*)e_s;
#pragma unroll
        for (int t = 0; t < 4; ++t) {
            float4 a = w1r[t * 64 + lane];
            float4 ee = ev[t * 64 + lane];
            s1 += a.x * ee.x + a.y * ee.y + a.z * ee.z + a.w * ee.w;
        }
    }
    s1 = waveReduceSum(s1);
    if (lane == 0) {
        float r = tanhf(s1 / (*Ls) + t2[j]);
        if (isBf16) ((__hip_bfloat16*)out)[j] = __float2bfloat16(r);
        else        ((float*)out)[j] = r;
    }
}

extern "C" void kernel_launch(void* const* d_in, const int* in_sizes, int n_in,
                              void* d_out, int out_size, void* d_ws, size_t ws_size,
                              hipStream_t stream) {
    const void* H  = d_in[0];
    const void* ht = d_in[1];
    const void* W0 = d_in[2];
    const void* b0 = d_in[3];
    const void* W1 = d_in[4];
    const void* b1 = d_in[5];
    const void* W2 = d_in[6];
    const void* b2 = d_in[7];
    int N = in_sizes[0] / D;

    float* wsf    = (float*)d_ws;
    int*   counter= (int*)wsf;        // [1]
    float* Ls     = wsf + 1;          // [1]
    float* q      = wsf + 64;         // [1024]
    float* t2     = wsf + 1088;       // [1024]
    float* e_s    = wsf + 2112;       // [1024]
    float* lvals  = wsf + 3136;       // [PB]
    float* accp   = wsf + 4160;       // [PB][1024] (16B-aligned)

    k_q<<<256, 512, 0, stream>>>(W0, b0, W2, b1, b2, ht, q, t2, counter);
    k_pass<<<PB, 512, 0, stream>>>(H, ht, q, accp, lvals, e_s, Ls, counter, N);
    k_out<<<256, 256, 0, stream>>>(W1, ht, e_s, t2, Ls, d_out);
}

// Round 7
// 301.713 us; speedup vs baseline: 1.6015x; 1.6015x over previous
//
#include <hip/hip_runtime.h>
#include <hip/hip_bf16.h>

#define D 1024

typedef unsigned int u32;
typedef __attribute__((ext_vector_type(4))) unsigned int u32x4;

__device__ __forceinline__ float bflo(u32 u) { return __uint_as_float(u << 16); }
__device__ __forceinline__ float bfhi(u32 u) { return __uint_as_float(u & 0xffff0000u); }
__device__ __forceinline__ float bf1(const void* p, int j) {
    unsigned short s = ((const unsigned short*)p)[j];
    return __uint_as_float(((u32)s) << 16);
}

__device__ __forceinline__ float waveReduceSum(float v) {
#pragma unroll
    for (int off = 32; off > 0; off >>= 1) v += __shfl_xor(v, off, 64);
    return v;
}

__device__ __forceinline__ float rowDotHt(const void* W, const void* ht,
                                          int j, int lane, int isBf16) {
    float s = 0.f;
    if (isBf16) {
        const u32x4* wrow = (const u32x4*)((const __hip_bfloat16*)W + (size_t)j * D);
        const u32x4* hv = (const u32x4*)ht;
#pragma unroll
        for (int half = 0; half < 2; ++half) {
            u32x4 a = wrow[half * 64 + lane];
            u32x4 b = hv[half * 64 + lane];
#pragma unroll
            for (int t = 0; t < 4; ++t) {
                s += bflo(a[t]) * bflo(b[t]);
                s += bfhi(a[t]) * bfhi(b[t]);
            }
        }
    } else {
        const float4* wrow = (const float4*)((const float*)W + (size_t)j * D);
        const float4* hv = (const float4*)ht;
#pragma unroll
        for (int t = 0; t < 4; ++t) {
            float4 a = wrow[t * 64 + lane];
            float4 b = hv[t * 64 + lane];
            s += a.x * b.x + a.y * b.y + a.z * b.z + a.w * b.w;
        }
    }
    return waveReduceSum(s);
}

// waves 0-3: q[j] = W0[j].h_t + b0[j]; waves 4-7: t2[j] = W2[j].h_t + b1[j] + b2[j].
// Inline dtype probe (bf16 low-half exponents sane); block 0 stores flag, zeros e_s/Ls.
__global__ __launch_bounds__(512) void k_q(const void* __restrict__ W0,
                                           const void* __restrict__ b0,
                                           const void* __restrict__ W2,
                                           const void* __restrict__ b1,
                                           const void* __restrict__ b2,
                                           const void* __restrict__ ht,
                                           float* __restrict__ q,
                                           float* __restrict__ t2,
                                           int* __restrict__ flag,
                                           float* __restrict__ Ls,
                                           float* __restrict__ e_s) {
    int wid = threadIdx.x >> 6, lane = threadIdx.x & 63;
    // per-wave dtype probe
    int isBf16;
    {
        u32 w = ((const u32*)ht)[lane];
        u32 e = (w >> 7) & 0xFF;
        float c = (e >= 100 && e <= 126) ? 1.f : 0.f;
        c = waveReduceSum(c);
        isBf16 = (c >= 56.f) ? 1 : 0;
    }
    if (blockIdx.x == 0) {
        for (int k = threadIdx.x; k < D; k += 512) e_s[k] = 0.f;
        if (threadIdx.x == 0) { *Ls = 0.f; *flag = isBf16; }
    }
    int j = blockIdx.x * 4 + (wid & 3);
    if (wid < 4) {
        float s = rowDotHt(W0, ht, j, lane, isBf16);
        if (lane == 0) {
            float bias = isBf16 ? bf1(b0, j) : ((const float*)b0)[j];
            q[j] = s + bias;
        }
    } else {
        float s = rowDotHt(W2, ht, j, lane, isBf16);
        if (lane == 0) {
            float bb = isBf16 ? (bf1(b1, j) + bf1(b2, j))
                              : (((const float*)b1)[j] + ((const float*)b2)[j]);
            t2[j] = s + bb;
        }
    }
}

// R2-proven body: single row per wave-iteration, w_i = exp(exp(H_i.q));
// per-block LDS combine -> one fp32 atomicAdd per element into e_s, Ls.
__global__ __launch_bounds__(512) void k_pass(const int* __restrict__ flag,
                                              const void* __restrict__ Hm,
                                              const float* __restrict__ q,
                                              float* __restrict__ e_s,
                                              float* __restrict__ Lp,
                                              int N, int totalWaves) {
    __shared__ float lacc[8][D];
    __shared__ float ll[8];
    int wid = threadIdx.x >> 6, lane = threadIdx.x & 63;
    int gw = blockIdx.x * 8 + wid;
    int isBf16 = *flag;

    int col[16];
    if (isBf16) {
#pragma unroll
        for (int j = 0; j < 8; ++j) { col[j] = lane * 8 + j; col[8 + j] = 512 + lane * 8 + j; }
    } else {
#pragma unroll
        for (int t = 0; t < 4; ++t)
#pragma unroll
            for (int u = 0; u < 4; ++u) col[t * 4 + u] = t * 256 + lane * 4 + u;
    }
    float qr[16];
#pragma unroll
    for (int j = 0; j < 16; ++j) qr[j] = q[col[j]];

    float l = 0.f;
    float acc[16];
#pragma unroll
    for (int j = 0; j < 16; ++j) acc[j] = 0.f;

    for (int r = gw; r < N; r += totalWaves) {
        float h[16];
        if (isBf16) {
            const u32x4* hr = (const u32x4*)((const __hip_bfloat16*)Hm + (size_t)r * D);
            u32x4 a = hr[lane];
            u32x4 b = hr[64 + lane];
#pragma unroll
            for (int t = 0; t < 4; ++t) {
                h[2 * t] = bflo(a[t]);     h[2 * t + 1] = bfhi(a[t]);
                h[8 + 2 * t] = bflo(b[t]); h[8 + 2 * t + 1] = bfhi(b[t]);
            }
        } else {
            const float4* hr = (const float4*)((const float*)Hm + (size_t)r * D);
#pragma unroll
            for (int t = 0; t < 4; ++t) {
                float4 a = hr[t * 64 + lane];
                h[t * 4 + 0] = a.x; h[t * 4 + 1] = a.y;
                h[t * 4 + 2] = a.z; h[t * 4 + 3] = a.w;
            }
        }
        float d = 0.f;
#pragma unroll
        for (int j = 0; j < 16; ++j) d += h[j] * qr[j];
        d = waveReduceSum(d);
        float p = __expf(__expf(d));  // raw-score exp, then softmax numerator (no shift)
        l += p;
#pragma unroll
        for (int j = 0; j < 16; ++j) acc[j] += p * h[j];
    }

    // block combine: 8 waves -> LDS -> one atomic per element
#pragma unroll
    for (int j = 0; j < 16; ++j) lacc[wid][col[j]] = acc[j];
    if (lane == 0) ll[wid] = l;
    __syncthreads();
    for (int k = threadIdx.x; k < D; k += 512) {
        float s = 0.f;
#pragma unroll
        for (int w = 0; w < 8; ++w) s += lacc[w][k];
        atomicAdd(&e_s[k], s);
    }
    if (threadIdx.x == 0) {
        float s = 0.f;
#pragma unroll
        for (int w = 0; w < 8; ++w) s += ll[w];
        atomicAdd(Lp, s);
    }
}

// out[j] = tanh(dot(W1[j], e_s)/Ls + t2[j])
__global__ __launch_bounds__(256) void k_out(const int* __restrict__ flag,
                                             const void* __restrict__ W1,
                                             const float* __restrict__ e_s,
                                             const float* __restrict__ t2,
                                             const float* __restrict__ Ls,
                                             void* __restrict__ out) {
    int wid = threadIdx.x >> 6, lane = threadIdx.x & 63;
    int j = blockIdx.x * 4 + wid;
    int isBf16 = *flag;
    float s1 = 0.f;
    if (isBf16) {
        const u32x4* w1r = (const u32x4*)((const __hip_bfloat16*)W1 + (size_t)j * D);
        int c0 = lane * 8;
#pragma unroll
        for (int half = 0; half < 2; ++half) {
            u32x4 a = w1r[half * 64 + lane];
            const float4* ev = (const float4*)(e_s + half * 512 + c0);
            float4 ea = ev[0], eb = ev[1];
            float e[8] = {ea.x, ea.y, ea.z, ea.w, eb.x, eb.y, eb.z, eb.w};
#pragma unroll
            for (int t = 0; t < 4; ++t)
                s1 += bflo(a[t]) * e[2 * t] + bfhi(a[t]) * e[2 * t + 1];
        }
    } else {
        const float4* w1r = (const float4*)((const float*)W1 + (size_t)j * D);
        const float4* ev = (const float4*)e_s;
#pragma unroll
        for (int t = 0; t < 4; ++t) {
            float4 a = w1r[t * 64 + lane];
            float4 ee = ev[t * 64 + lane];
            s1 += a.x * ee.x + a.y * ee.y + a.z * ee.z + a.w * ee.w;
        }
    }
    s1 = waveReduceSum(s1);
    if (lane == 0) {
        float r = tanhf(s1 / (*Ls) + t2[j]);
        if (isBf16) ((__hip_bfloat16*)out)[j] = __float2bfloat16(r);
        else        ((float*)out)[j] = r;
    }
}

extern "C" void kernel_launch(void* const* d_in, const int* in_sizes, int n_in,
                              void* d_out, int out_size, void* d_ws, size_t ws_size,
                              hipStream_t stream) {
    const void* H  = d_in[0];
    const void* ht = d_in[1];
    const void* W0 = d_in[2];
    const void* b0 = d_in[3];
    const void* W1 = d_in[4];
    const void* b1 = d_in[5];
    const void* W2 = d_in[6];
    const void* b2 = d_in[7];
    int N = in_sizes[0] / D;

    float* wsf   = (float*)d_ws;
    int*   flag  = (int*)wsf;         // [1]
    float* Ls    = wsf + 1;           // [1]
    float* q     = wsf + 64;          // [1024]
    float* t2    = wsf + 1088;        // [1024]
    float* e_s   = wsf + 2112;        // [1024] (16B-aligned)

    const int B = 512;  // k_pass blocks, 8 waves each

    k_q<<<256, 512, 0, stream>>>(W0, b0, W2, b1, b2, ht, q, t2, flag, Ls, e_s);
    k_pass<<<B, 512, 0, stream>>>(flag, H, q, e_s, Ls, N, B * 8);
    k_out<<<256, 256, 0, stream>>>(flag, W1, e_s, t2, Ls, d_out);
}